// Round 12
// baseline (77.017 us; speedup 1.0000x reference)
//
#include <hip/hip_runtime.h>
#include <hip/hip_bf16.h>

typedef __bf16 bf16x8 __attribute__((ext_vector_type(8)));
typedef float floatx4 __attribute__((ext_vector_type(4)));

#define BM 256
#define BN 128
#define BK 32
#define A_TILE (BM * BK)   // 8192 ushorts = 16 KB
#define B_TILE (BN * BK)   // 4096 ushorts = 8 KB
#define EPS 1e-5f

// ------------- f32 -> bf16 conversion, x and w fused in one launch ----------
__global__ void cvt_f32_to_bf16_2(const float* __restrict__ inx, ushort* __restrict__ outx, int n4x,
                                  const float* __restrict__ inw, ushort* __restrict__ outw, int n4w) {
    int i = blockIdx.x * blockDim.x + threadIdx.x;
    int stride = gridDim.x * blockDim.x;
    int total = n4x + n4w;
    for (; i < total; i += stride) {
        const float4* src = (i < n4x) ? &reinterpret_cast<const float4*>(inx)[i]
                                      : &reinterpret_cast<const float4*>(inw)[i - n4x];
        ushort4* dst = (i < n4x) ? &reinterpret_cast<ushort4*>(outx)[i]
                                 : &reinterpret_cast<ushort4*>(outw)[i - n4x];
        float4 v = *src;
        ushort4 o;
        o.x = __builtin_bit_cast(unsigned short, __float2bfloat16(v.x));
        o.y = __builtin_bit_cast(unsigned short, __float2bfloat16(v.y));
        o.z = __builtin_bit_cast(unsigned short, __float2bfloat16(v.z));
        o.w = __builtin_bit_cast(unsigned short, __float2bfloat16(v.w));
        *dst = o;
    }
}

// ---------------- fold BN+scale into per-column alpha/bias ------------------
__global__ void bn_fold(const float* __restrict__ scale,
                        const float* __restrict__ mean,
                        const float* __restrict__ var,
                        const float* __restrict__ gamma,
                        const float* __restrict__ beta,
                        float* __restrict__ alpha,
                        float* __restrict__ bias, int n) {
    int i = blockIdx.x * blockDim.x + threadIdx.x;
    if (i < n) {
        float rs = rsqrtf(var[i] + EPS);
        float g = gamma[i] * rs;
        alpha[i] = scale[i] * g;
        bias[i]  = beta[i] - mean[i] * g;
    }
}

__device__ __forceinline__ void gload_lds16(const ushort* g, ushort* l) {
    __builtin_amdgcn_global_load_lds(
        (const __attribute__((address_space(1))) void*)g,
        (__attribute__((address_space(3))) void*)l, 16, 0, 0);
}

// -- bf16 MFMA GEMM: 256x128, BK=32, dbuf-2, 2 blocks/CU (occupancy lever) ---
// C[m][n] = sum_k A[m][k]*B[n][k]; epilogue C = C*alpha[n] + bias[n].
//
// R4..R11 verdict: at 1 block/CU (144KB LDS) every schedule lands 47.5-58us;
// MfmaUtil caps ~27% because each vmcnt/barrier boundary stalls the whole CU
// (2 waves/SIMD, no co-resident block). This round isolates OCCUPANCY:
// 48 KB LDS/block -> 2 blocks/CU (4 waves/SIMD). Catalog "minimum 2-phase"
// loop (T3 recipe): STAGE(next->buf^1); compute buf; vmcnt(0); barrier.
// Block Y's MFMA covers block X's boundary drain (m114 cross-block overlap).
//
// LDS swizzle (R7-verified at BK=32): rows are 64B = 4 chunks of 16B;
// phys_chunk = logical_chunk ^ ((row>>1)&3); source pre-swizzled
// (scol = ((lane&3)^((lane>>3)&3))*8), reads XOR'd (pc = (hi^((fr>>1)&3))*8).
// R7 measured: SQ_LDS_BANK_CONFLICT = 0.
__global__ __launch_bounds__(512, 4) void gemm_bf16_bn(
    const ushort* __restrict__ A,   // [M][K] bf16 bits
    const ushort* __restrict__ B,   // [N][K] bf16 bits
    const float* __restrict__ alpha,
    const float* __restrict__ bias,
    float* __restrict__ C, int M, int N, int K) {
    __shared__ ushort As[2 * A_TILE];   // 32 KB
    __shared__ ushort Bs[2 * B_TILE];   // 16 KB

    const int tid  = threadIdx.x;
    const int wid  = tid >> 6;
    const int lane = tid & 63;

    // bijective XCD-aware block swizzle (m204)
    const int nwg  = (int)gridDim.x;
    const int orig = (int)blockIdx.x;
    const int q = nwg >> 3, rr = nwg & 7;
    const int xcd = orig & 7;
    const int swz = ((xcd < rr) ? xcd * (q + 1) : rr * (q + 1) + (xcd - rr) * q)
                    + (orig >> 3);
    const int nTilesN = N / BN;
    const int brow = (swz / nTilesN) * BM;
    const int bcol = (swz % nTilesN) * BN;

    // 8 waves = 4M x 2N, each owns a 64x64 output sub-tile
    const int wr = (wid >> 1) * 64;
    const int wc = (wid & 1) * 64;
    const int fr = lane & 15;
    const int hi = lane >> 4;

    // fragment LDS offsets (ushort units), loop-invariant, swizzled (R7 map)
    int offA[4], offB[4];
    const int pc = (hi ^ ((fr >> 1) & 3)) * 8;
#pragma unroll
    for (int m = 0; m < 4; ++m) offA[m] = (wr + m * 16 + fr) * BK + pc;
#pragma unroll
    for (int n = 0; n < 4; ++n) offB[n] = (wc + n * 16 + fr) * BK + pc;

    // staging: 512 thr x 16B = 8 KB round = 128 rows of 64 B.
    // thread t: row = wid*16 + (lane>>2), phys chunk = lane&3;
    // source chunk pre-swizzled: (lane&3) ^ ((lane>>3)&3)   [row>>1&3]
    const int srow = wid * 16 + (lane >> 2);
    const int scol = ((lane & 3) ^ ((lane >> 3) & 3)) * 8;
    const ushort* aSrc = A + (size_t)(brow + srow) * K + scol;
    const ushort* bSrc = B + (size_t)(bcol + srow) * K + scol;
    const int stDst = wid * 512;   // wave-uniform LDS base (HW adds lane*16B)

    floatx4 acc[4][4];
#pragma unroll
    for (int m = 0; m < 4; ++m)
#pragma unroll
        for (int n = 0; n < 4; ++n) acc[m][n] = (floatx4)0.0f;

    auto STAGE = [&](int koff, int bufsel) {   // 3 gloads: A 2 rounds, B 1
        ushort* da = As + bufsel * A_TILE + stDst;
        ushort* db = Bs + bufsel * B_TILE + stDst;
        const ushort* sa = aSrc + koff;
        gload_lds16(sa,                    da);
        gload_lds16(sa + (size_t)128 * K,  da + 4096);
        gload_lds16(bSrc + koff,           db);
    };

    auto LOADF = [&](int bufsel, bf16x8 (&af)[4], bf16x8 (&bf)[4]) {
        const ushort* pA = As + bufsel * A_TILE;
        const ushort* pB = Bs + bufsel * B_TILE;
#pragma unroll
        for (int m = 0; m < 4; ++m) af[m] = *(const bf16x8*)(pA + offA[m]);
#pragma unroll
        for (int n = 0; n < 4; ++n) bf[n] = *(const bf16x8*)(pB + offB[n]);
    };

    auto DOMFMA = [&](bf16x8 (&af)[4], bf16x8 (&bf)[4]) {
        __builtin_amdgcn_s_setprio(1);
#pragma unroll
        for (int m = 0; m < 4; ++m)
#pragma unroll
            for (int n = 0; n < 4; ++n)
                acc[m][n] = __builtin_amdgcn_mfma_f32_16x16x32_bf16(
                    af[m], bf[n], acc[m][n], 0, 0, 0);
        __builtin_amdgcn_s_setprio(0);
    };

    const int nK = K / BK;   // caller guarantees >= 2

    STAGE(0, 0);
    asm volatile("s_waitcnt vmcnt(0)" ::: "memory");   // tile 0 landed (own)
    __builtin_amdgcn_s_barrier();                      // all waves' tile 0
    asm volatile("" ::: "memory");

    int cur = 0;
    for (int kt = 0; kt < nK; ++kt) {
        if (kt + 1 < nK) STAGE((kt + 1) * BK, cur ^ 1);  // next tile -> other buf
        bf16x8 af[4], bf[4];
        LOADF(cur, af, bf);                 // 8 ds_read from live buf
        DOMFMA(af, bf);                     // compiler lgkm-guards af/bf
        if (kt + 1 < nK) {
            asm volatile("s_waitcnt vmcnt(0)" ::: "memory");  // next tile landed
            __builtin_amdgcn_s_barrier();   // block-wide: resident + buf read
            asm volatile("" ::: "memory");  //  done (MFMA consumed all reads)
        }
        cur ^= 1;
    }

    // epilogue: C/D layout col=lane&15, row=hi*4+j  [m89/m91 verified]
    float al[4], bi[4];
    const int ccol = bcol + wc + fr;
#pragma unroll
    for (int n = 0; n < 4; ++n) {
        al[n] = alpha[ccol + n * 16];
        bi[n] = bias[ccol + n * 16];
    }
    const int r0 = brow + wr + hi * 4;
#pragma unroll
    for (int m = 0; m < 4; ++m)
#pragma unroll
        for (int n = 0; n < 4; ++n)
#pragma unroll
            for (int j = 0; j < 4; ++j) {
                int row = r0 + m * 16 + j;
                int col = ccol + n * 16;
                C[(size_t)row * N + col] = acc[m][n][j] * al[n] + bi[n];
            }
}

// ---------------- safety fallback (fp32 vector, naive) ----------------------
__global__ void gemm_f32_naive(const float* __restrict__ A,
                               const float* __restrict__ B,
                               const float* __restrict__ scale,
                               const float* __restrict__ mean,
                               const float* __restrict__ var,
                               const float* __restrict__ gamma,
                               const float* __restrict__ beta,
                               float* __restrict__ C, int N, int K) {
    int o = blockIdx.x * blockDim.x + threadIdx.x;
    int b = blockIdx.y;
    if (o >= N) return;
    float s = 0.f;
    const float* a = A + (size_t)b * K;
    const float* w = B + (size_t)o * K;
    for (int k = 0; k < K; ++k) s += a[k] * w[k];
    float rs = rsqrtf(var[o] + EPS);
    float g = gamma[o] * rs;
    C[(size_t)b * N + o] = s * scale[o] * g + (beta[o] - mean[o] * g);
}

extern "C" void kernel_launch(void* const* d_in, const int* in_sizes, int n_in,
                              void* d_out, int out_size, void* d_ws, size_t ws_size,
                              hipStream_t stream) {
    const float* x     = (const float*)d_in[0];
    const float* w     = (const float*)d_in[1];
    const float* scale = (const float*)d_in[2];
    const float* mean  = (const float*)d_in[3];
    const float* var   = (const float*)d_in[4];
    const float* gamma = (const float*)d_in[5];
    const float* beta  = (const float*)d_in[6];
    float* out = (float*)d_out;

    const int OUT = in_sizes[2];
    const int IN  = in_sizes[1] / OUT;
    const int Bsz = in_sizes[0] / IN;

    const size_t xElems = (size_t)Bsz * IN;
    const size_t wElems = (size_t)OUT * IN;
    const size_t need = xElems * 2 + wElems * 2 + (size_t)OUT * 8;

    const bool tiled_ok = (Bsz % BM == 0) && (OUT % BN == 0) &&
                          (IN % BK == 0) && (IN / BK >= 2) &&
                          (ws_size >= need);

    if (!tiled_ok) {
        dim3 grid((OUT + 255) / 256, Bsz);
        gemm_f32_naive<<<grid, 256, 0, stream>>>(x, w, scale, mean, var, gamma,
                                                 beta, out, OUT, IN);
        return;
    }

    ushort* xb = (ushort*)d_ws;
    ushort* wb = xb + xElems;
    float* alpha = (float*)(wb + wElems);
    float* bias  = alpha + OUT;

    cvt_f32_to_bf16_2<<<2048, 256, 0, stream>>>(x, xb, (int)(xElems / 4),
                                                w, wb, (int)(wElems / 4));
    bn_fold<<<(OUT + 255) / 256, 256, 0, stream>>>(scale, mean, var, gamma, beta,
                                                   alpha, bias, OUT);

    dim3 grid((Bsz / BM) * (OUT / BN));
    gemm_bf16_bn<<<grid, 512, 0, stream>>>(xb, wb, alpha, bias, out, Bsz, OUT, IN);
}

// Round 15
// 57.829 us; speedup vs baseline: 1.3318x; 1.3318x over previous
//
#include <hip/hip_runtime.h>
#include <hip/hip_bf16.h>

typedef __bf16 bf16x8 __attribute__((ext_vector_type(8)));
typedef float floatx4 __attribute__((ext_vector_type(4)));

#define BM 256
#define BN 128
#define BK 64
#define A_TILE (BM * BK)   // 16384 ushorts = 32 KB
#define B_TILE (BN * BK)   // 8192 ushorts  = 16 KB
#define EPS 1e-5f

// ---------------- f32 -> bf16 conversion (vectorized, grid-stride) ----------
__global__ void cvt_f32_to_bf16(const float* __restrict__ in,
                                ushort* __restrict__ out, int n4) {
    int i = blockIdx.x * blockDim.x + threadIdx.x;
    int stride = gridDim.x * blockDim.x;
    for (; i < n4; i += stride) {
        float4 v = reinterpret_cast<const float4*>(in)[i];
        ushort4 o;
        o.x = __builtin_bit_cast(unsigned short, __float2bfloat16(v.x));
        o.y = __builtin_bit_cast(unsigned short, __float2bfloat16(v.y));
        o.z = __builtin_bit_cast(unsigned short, __float2bfloat16(v.z));
        o.w = __builtin_bit_cast(unsigned short, __float2bfloat16(v.w));
        reinterpret_cast<ushort4*>(out)[i] = o;
    }
}

// ---------------- fold BN+scale into per-column alpha/bias ------------------
__global__ void bn_fold(const float* __restrict__ scale,
                        const float* __restrict__ mean,
                        const float* __restrict__ var,
                        const float* __restrict__ gamma,
                        const float* __restrict__ beta,
                        float* __restrict__ alpha,
                        float* __restrict__ bias, int n) {
    int i = blockIdx.x * blockDim.x + threadIdx.x;
    if (i < n) {
        float rs = rsqrtf(var[i] + EPS);
        float g = gamma[i] * rs;
        alpha[i] = scale[i] * g;
        bias[i]  = beta[i] - mean[i] * g;
    }
}

__device__ __forceinline__ void gload_lds16(const ushort* g, ushort* l) {
    __builtin_amdgcn_global_load_lds(
        (const __attribute__((address_space(1))) void*)g,
        (__attribute__((address_space(3))) void*)l, 16, 0, 0);
}

// ---------------- bf16 MFMA GEMM: 256x128, BK=64, fine 2-phase/K-tile -------
// C[m][n] = sum_k A[m][k]*B[n][k]; epilogue C = C*alpha[n] + bias[n].
// BEST MEASURED (R9): GEMM 47.5us, total 57.34us, MfmaUtil 27%, conflicts 0.
// R10 (fat waves, 1 wave/SIMD): 57.7us. R11 (1-barrier overlap + vmcnt(0)
// drains): 55.5us. R12 (BK=32 dbuf, 2 blk/CU attempt): 65.5us. All deviations
// regressed -> this structure is the measured optimum of the family.
//
// Structure per K-tile t (cur = t%3):
//   phase s=0,1:
//     8 x ds_read_b128  (frags of kstep s, buf cur)   // compiler lgkm-guards
//     3 x global_load_lds (tile t+2 -> buf (t+2)%3)   // never a live buffer
//     s_barrier                                       // phase alignment
//     setprio(1); 16 x MFMA(kstep s); setprio(0)      // cross-wave pipelining
//     s_barrier
//   tile end: s_waitcnt vmcnt(6); s_barrier           // tile t+1 resident
//
// LDS swizzle (T2, rule #21 both-sides): phys chunk = logical chunk ^ (row&7),
// pre-swizzled on the global source, same XOR on reads. Measured: conflicts 0.
__global__ __launch_bounds__(512, 2) void gemm_bf16_bn(
    const ushort* __restrict__ A,   // [M][K] bf16 bits
    const ushort* __restrict__ B,   // [N][K] bf16 bits
    const float* __restrict__ alpha,
    const float* __restrict__ bias,
    float* __restrict__ C, int M, int N, int K) {
    __shared__ ushort As[3 * A_TILE];   // 96 KB
    __shared__ ushort Bs[3 * B_TILE];   // 48 KB

    const int tid  = threadIdx.x;
    const int wid  = tid >> 6;
    const int lane = tid & 63;

    // bijective XCD-aware block swizzle (m204)
    const int nwg  = (int)gridDim.x;
    const int orig = (int)blockIdx.x;
    const int q = nwg >> 3, rr = nwg & 7;
    const int xcd = orig & 7;
    const int swz = ((xcd < rr) ? xcd * (q + 1) : rr * (q + 1) + (xcd - rr) * q)
                    + (orig >> 3);
    const int nTilesN = N / BN;
    const int brow = (swz / nTilesN) * BM;
    const int bcol = (swz % nTilesN) * BN;

    // 8 waves = 4M x 2N, each owns a 64x64 output sub-tile
    const int wr = (wid >> 1) * 64;
    const int wc = (wid & 1) * 64;
    const int fr = lane & 15;
    const int hi = lane >> 4;

    // fragment LDS offsets (ushort units), loop-invariant, swizzled
    int offA[2][4], offB[2][4];
#pragma unroll
    for (int s = 0; s < 2; ++s) {
#pragma unroll
        for (int m = 0; m < 4; ++m) {
            int row = wr + m * 16 + fr;                  // row&7 == fr&7
            offA[s][m] = row * BK + (((s * 4 + hi) ^ (fr & 7)) * 8);
        }
#pragma unroll
        for (int n = 0; n < 4; ++n) {
            int row = wc + n * 16 + fr;
            offB[s][n] = row * BK + (((s * 4 + hi) ^ (fr & 7)) * 8);
        }
    }

    // staging: per 8 KB round (64 rows), thread t -> row t>>3, chunk t&7;
    // source chunk pre-swizzled: (lane&7) ^ (lane>>3)  [row&7 == lane>>3]
    const int srow = wid * 8 + (lane >> 3);
    const int scol = ((lane & 7) ^ (lane >> 3)) * 8;
    const ushort* aSrc = A + (size_t)(brow + srow) * K + scol;
    const ushort* bSrc = B + (size_t)(bcol + srow) * K + scol;
    const int stDst = wid * 512;   // wave-uniform LDS base (HW adds lane*16B)

    floatx4 acc[4][4];
#pragma unroll
    for (int m = 0; m < 4; ++m)
#pragma unroll
        for (int n = 0; n < 4; ++n) acc[m][n] = (floatx4)0.0f;

    // staging halves: ph0 = A rounds 0..2, ph1 = A round 3 + B rounds 0..1
    auto STAGE_P0 = [&](int koff, int bufsel) {
        ushort* da = As + bufsel * A_TILE + stDst;
        const ushort* sa = aSrc + koff;
        gload_lds16(sa,                   da);
        gload_lds16(sa + (size_t)64  * K, da + 4096);
        gload_lds16(sa + (size_t)128 * K, da + 8192);
    };
    auto STAGE_P1 = [&](int koff, int bufsel) {
        ushort* da = As + bufsel * A_TILE + stDst;
        ushort* db = Bs + bufsel * B_TILE + stDst;
        const ushort* sa = aSrc + koff;
        const ushort* sb = bSrc + koff;
        gload_lds16(sa + (size_t)192 * K, da + 12288);
        gload_lds16(sb,                   db);
        gload_lds16(sb + (size_t)64  * K, db + 4096);
    };

    auto LOADF = [&](int bufsel, int s, bf16x8 (&af)[4], bf16x8 (&bf)[4]) {
        const ushort* pA = As + bufsel * A_TILE;
        const ushort* pB = Bs + bufsel * B_TILE;
#pragma unroll
        for (int m = 0; m < 4; ++m) af[m] = *(const bf16x8*)(pA + offA[s][m]);
#pragma unroll
        for (int n = 0; n < 4; ++n) bf[n] = *(const bf16x8*)(pB + offB[s][n]);
    };

    auto DOMFMA = [&](bf16x8 (&af)[4], bf16x8 (&bf)[4]) {
        __builtin_amdgcn_s_setprio(1);
#pragma unroll
        for (int m = 0; m < 4; ++m)
#pragma unroll
            for (int n = 0; n < 4; ++n)
                acc[m][n] = __builtin_amdgcn_mfma_f32_16x16x32_bf16(
                    af[m], bf[n], acc[m][n], 0, 0, 0);
        __builtin_amdgcn_s_setprio(0);
    };

    const int nK = K / BK;   // caller guarantees >= 4

    STAGE_P0(0, 0);  STAGE_P1(0, 0);
    STAGE_P0(BK, 1); STAGE_P1(BK, 1);
    asm volatile("s_waitcnt vmcnt(6)" ::: "memory");   // tile 0 landed (own)
    __builtin_amdgcn_s_barrier();                      // all waves' tile 0
    asm volatile("" ::: "memory");

    int cur = 0;
    for (int kt = 0; kt < nK; ++kt) {
        int tgt = cur + 2; if (tgt >= 3) tgt -= 3;
        const bool st = (kt + 2 < nK);
        bf16x8 af[4], bf[4];
        // ---- phase 0 ----
        LOADF(cur, 0, af, bf);
        if (st) STAGE_P0((kt + 2) * BK, tgt);
        asm volatile("" ::: "memory");
        __builtin_amdgcn_s_barrier();
        asm volatile("" ::: "memory");
        DOMFMA(af, bf);                     // compiler lgkm-guards af/bf
        asm volatile("" ::: "memory");
        __builtin_amdgcn_s_barrier();
        asm volatile("" ::: "memory");
        // ---- phase 1 ----
        LOADF(cur, 1, af, bf);
        if (st) STAGE_P1((kt + 2) * BK, tgt);
        asm volatile("" ::: "memory");
        __builtin_amdgcn_s_barrier();
        asm volatile("" ::: "memory");
        DOMFMA(af, bf);
        // ---- tile boundary: next tile resident? ----
        if (kt + 1 < nK) {
            if (st) asm volatile("s_waitcnt vmcnt(6)" ::: "memory");
            else    asm volatile("s_waitcnt vmcnt(0)" ::: "memory");
        }
        asm volatile("" ::: "memory");
        __builtin_amdgcn_s_barrier();
        asm volatile("" ::: "memory");
        cur = cur + 1; if (cur >= 3) cur = 0;
    }

    // epilogue: C/D layout col=lane&15, row=hi*4+j  [m89/m91 verified]
    float al[4], bi[4];
    const int ccol = bcol + wc + fr;
#pragma unroll
    for (int n = 0; n < 4; ++n) {
        al[n] = alpha[ccol + n * 16];
        bi[n] = bias[ccol + n * 16];
    }
    const int r0 = brow + wr + hi * 4;
#pragma unroll
    for (int m = 0; m < 4; ++m)
#pragma unroll
        for (int n = 0; n < 4; ++n)
#pragma unroll
            for (int j = 0; j < 4; ++j) {
                int row = r0 + m * 16 + j;
                int col = ccol + n * 16;
                C[(size_t)row * N + col] = acc[m][n][j] * al[n] + bi[n];
            }
}

// ---------------- safety fallback (fp32 vector, naive) ----------------------
__global__ void gemm_f32_naive(const float* __restrict__ A,
                               const float* __restrict__ B,
                               const float* __restrict__ scale,
                               const float* __restrict__ mean,
                               const float* __restrict__ var,
                               const float* __restrict__ gamma,
                               const float* __restrict__ beta,
                               float* __restrict__ C, int N, int K) {
    int o = blockIdx.x * blockDim.x + threadIdx.x;
    int b = blockIdx.y;
    if (o >= N) return;
    float s = 0.f;
    const float* a = A + (size_t)b * K;
    const float* w = B + (size_t)o * K;
    for (int k = 0; k < K; ++k) s += a[k] * w[k];
    float rs = rsqrtf(var[o] + EPS);
    float g = gamma[o] * rs;
    C[(size_t)b * N + o] = s * scale[o] * g + (beta[o] - mean[o] * g);
}

extern "C" void kernel_launch(void* const* d_in, const int* in_sizes, int n_in,
                              void* d_out, int out_size, void* d_ws, size_t ws_size,
                              hipStream_t stream) {
    const float* x     = (const float*)d_in[0];
    const float* w     = (const float*)d_in[1];
    const float* scale = (const float*)d_in[2];
    const float* mean  = (const float*)d_in[3];
    const float* var   = (const float*)d_in[4];
    const float* gamma = (const float*)d_in[5];
    const float* beta  = (const float*)d_in[6];
    float* out = (float*)d_out;

    const int OUT = in_sizes[2];
    const int IN  = in_sizes[1] / OUT;
    const int Bsz = in_sizes[0] / IN;

    const size_t xElems = (size_t)Bsz * IN;
    const size_t wElems = (size_t)OUT * IN;
    const size_t need = xElems * 2 + wElems * 2 + (size_t)OUT * 8;

    const bool tiled_ok = (Bsz % BM == 0) && (OUT % BN == 0) &&
                          (IN % BK == 0) && (IN / BK >= 4) &&
                          (ws_size >= need);

    if (!tiled_ok) {
        dim3 grid((OUT + 255) / 256, Bsz);
        gemm_f32_naive<<<grid, 256, 0, stream>>>(x, w, scale, mean, var, gamma,
                                                 beta, out, OUT, IN);
        return;
    }

    ushort* xb = (ushort*)d_ws;
    ushort* wb = xb + xElems;
    float* alpha = (float*)(wb + wElems);
    float* bias  = alpha + OUT;

    cvt_f32_to_bf16<<<2048, 256, 0, stream>>>(x, xb, (int)(xElems / 4));
    cvt_f32_to_bf16<<<2048, 256, 0, stream>>>(w, wb, (int)(wElems / 4));
    bn_fold<<<(OUT + 255) / 256, 256, 0, stream>>>(scale, mean, var, gamma, beta,
                                                   alpha, bias, OUT);

    dim3 grid((Bsz / BM) * (OUT / BN));
    gemm_bf16_bn<<<grid, 512, 0, stream>>>(xb, wb, alpha, bias, out, Bsz, OUT, IN);
}